// Round 4
// baseline (74.316 us; speedup 1.0000x reference)
//
#include <hip/hip_runtime.h>

typedef unsigned short u16;
typedef __bf16 bf16x8 __attribute__((ext_vector_type(8)));
typedef float f32x16 __attribute__((ext_vector_type(16)));

union B8 { bf16x8 v; u16 s[8]; unsigned u[4]; uint4 u4; };

__device__ __forceinline__ unsigned cvtpk(float a, float b) {
    unsigned r;
    asm("v_cvt_pk_bf16_f32 %0, %1, %2" : "=v"(r) : "v"(a), "v"(b));
    return r;
}
__device__ __forceinline__ float ex2(float x) { return __builtin_amdgcn_exp2f(x); }
__device__ __forceinline__ void swap32(unsigned &a, unsigned &b) {
    asm("v_permlane32_swap_b32 %0, %1" : "+v"(a), "+v"(b));
}
__device__ __forceinline__ B8 load_w8(const float* __restrict__ p, float s) {
    float4 lo = ((const float4*)p)[0];
    float4 hi = ((const float4*)p)[1];
    B8 r;
    r.u[0] = cvtpk(lo.x * s, lo.y * s);
    r.u[1] = cvtpk(lo.z * s, lo.w * s);
    r.u[2] = cvtpk(hi.x * s, hi.y * s);
    r.u[3] = cvtpk(hi.z * s, hi.w * s);
    return r;
}
__device__ __forceinline__ f32x16 mfma32(const B8 a, const B8 b, f32x16 c) {
    return __builtin_amdgcn_mfma_f32_32x32x16_bf16(a.v, b.v, c, 0, 0, 0);
}
// K LDS: [512 tok][32 ck] u16, 4x16B slots per row XOR-swizzled by (tok>>1)&3
__device__ __forceinline__ int kidx(int row, int sl) {
    return row * 32 + (((sl ^ (row >> 1)) & 3) << 3);
}
// D-regs (rows (r&3)+8*(r>>2)+4*h5) -> two B-fragments (k-chunks of 16) via cvtpk+permlane
__device__ __forceinline__ void build_b(const float* p, B8& b0, B8& b1) {
    unsigned c0 = cvtpk(p[0], p[1]),   c1 = cvtpk(p[2], p[3]);
    unsigned c2 = cvtpk(p[4], p[5]),   c3 = cvtpk(p[6], p[7]);
    unsigned c4 = cvtpk(p[8], p[9]),   c5 = cvtpk(p[10], p[11]);
    unsigned c6 = cvtpk(p[12], p[13]), c7 = cvtpk(p[14], p[15]);
    swap32(c0, c2); swap32(c1, c3); swap32(c4, c6); swap32(c5, c7);
    b0.u[0] = c0; b0.u[1] = c1; b0.u[2] = c2; b0.u[3] = c3;
    b1.u[0] = c4; b1.u[1] = c5; b1.u[2] = c6; b1.u[3] = c7;
}

// LDS (u16 idx): K [512][32] @0 (32768B) | V [64][520] @16384 (66560B) | X [256][72] @49664 (36864B)
// epilogue: 16 wave-slots of 8KB f32 fout overlay @byte 0 (after barrier 5)
#define VOFF 16384
#define XOFF 49664
#define NSM  68096

__global__ __launch_bounds__(1024, 4)
void psab_fused(const float* __restrict__ x,
                const float* __restrict__ wk, const float* __restrict__ bk,
                const float* __restrict__ wv, const float* __restrict__ bv,
                const float* __restrict__ wo, const float* __restrict__ bo,
                float* __restrict__ out)
{
    __shared__ __align__(16) u16 smem[NSM];
    const int t    = threadIdx.x;
    const int lane = t & 63;
    const int wid  = t >> 6;        // 16 waves
    const int cl   = lane & 31;
    const int h5   = lane >> 5;

    const int bid = blockIdx.x;
    const int n   = (bid & 7) * 64 + (bid >> 3);   // XCD-bijective swizzle
    const int sh = n >> 6, sw = (n >> 3) & 7, sd = n & 7;
    const size_t base_vox = (size_t)(sh * 8) * 4096 + (size_t)(sw * 8) * 64 + (size_t)(sd * 8);

    const float WSC = 0.50506330f;   // sqrt(log2(e)/sqrt(32)) folded into K weights

    const int pair = wid >> 1;       // token group in projection
    const int kv   = wid & 1;        // 0 = K-proj wave, 1 = V-proj wave

    B8 wB[8];
    float bkv[16];
    float vb0 = 0.f, vb1 = 0.f;
    if (kv == 0) {
#pragma unroll
        for (int kc = 0; kc < 4; ++kc)
            wB[kc] = load_w8(wk + cl * 64 + kc * 16 + h5 * 8, WSC);
#pragma unroll
        for (int r = 0; r < 16; ++r)
            bkv[r] = bk[(r & 3) + 8 * (r >> 2) + 4 * h5] * WSC;
    } else {
#pragma unroll
        for (int nb = 0; nb < 2; ++nb)
#pragma unroll
            for (int kc = 0; kc < 4; ++kc)
                wB[nb * 4 + kc] = load_w8(wv + (nb * 32 + cl) * 64 + kc * 16 + h5 * 8, 1.0f);
        vb0 = bv[cl]; vb1 = bv[32 + cl];
    }

    const f32x16 z16 = {0,0,0,0,0,0,0,0,0,0,0,0,0,0,0,0};

    // ---- X staging: 2 chunks x 256 tok; thread (cS = ch, r3 = row-slot), 2 rows each ----
    const int cS = t & 63;
    const int r3 = t >> 6;           // 0..15
    float4 L4[2], H4[2];
#define LDX(cc)                                                                               \
    _Pragma("unroll")                                                                         \
    for (int i = 0; i < 2; ++i) {                                                             \
        const int rr = r3 + i * 16;                                                           \
        const float* gp = x + (size_t)cS * 262144 + base_vox                                  \
                        + ((cc) * 4 + (rr >> 3)) * 4096 + (rr & 7) * 64;                      \
        L4[i] = ((const float4*)gp)[0];                                                       \
        H4[i] = ((const float4*)gp)[1];                                                       \
    }
#define STX()                                                                                 \
    _Pragma("unroll")                                                                         \
    for (int i = 0; i < 2; ++i) {                                                             \
        const int rr = r3 + i * 16;                                                           \
        unsigned a0 = cvtpk(L4[i].x, L4[i].y), a1 = cvtpk(L4[i].z, L4[i].w);                  \
        unsigned a2 = cvtpk(H4[i].x, H4[i].y), a3 = cvtpk(H4[i].z, H4[i].w);                  \
        u16* xp = &smem[XOFF + (rr * 8) * 72 + cS];                                           \
        xp[0 * 72] = (u16)a0; xp[1 * 72] = (u16)(a0 >> 16);                                   \
        xp[2 * 72] = (u16)a1; xp[3 * 72] = (u16)(a1 >> 16);                                   \
        xp[4 * 72] = (u16)a2; xp[5 * 72] = (u16)(a2 >> 16);                                   \
        xp[6 * 72] = (u16)a3; xp[7 * 72] = (u16)(a3 >> 16);                                   \
    }

    LDX(0)
    STX()
    __syncthreads();                          // (1) X0 visible
    LDX(1)                                    // prefetch chunk1 under proj-chunk0 compute

#pragma unroll
    for (int cc = 0; cc < 2; ++cc) {
        const int tokb = cc * 256 + pair * 32;
        B8 ax[4];
#pragma unroll
        for (int kc = 0; kc < 4; ++kc)
            ax[kc].u4 = *(const uint4*)&smem[XOFF + (pair * 32 + cl) * 72 + kc * 16 + h5 * 8];
        if (kv == 0) {
            // K proj, swapped operands: D col = tok = cl, rows = ck -> packed uint2 stores
            f32x16 kd = mfma32(wB[0], ax[0], z16);
            kd = mfma32(wB[1], ax[1], kd);
            kd = mfma32(wB[2], ax[2], kd);
            kd = mfma32(wB[3], ax[3], kd);
            const int trow = tokb + cl;
#pragma unroll
            for (int g = 0; g < 4; ++g) {
                uint2 pk;
                pk.x = cvtpk(kd[4 * g + 0] + bkv[4 * g + 0], kd[4 * g + 1] + bkv[4 * g + 1]);
                pk.y = cvtpk(kd[4 * g + 2] + bkv[4 * g + 2], kd[4 * g + 3] + bkv[4 * g + 3]);
                *(uint2*)&smem[kidx(trow, g) + 4 * h5] = pk;
            }
        } else {
            // V proj: D col = cv = cl, rows = tok -> V^T[cv][tok] packed uint2
#pragma unroll
            for (int nb = 0; nb < 2; ++nb) {
                f32x16 vd = mfma32(ax[0], wB[nb * 4 + 0], z16);
                vd = mfma32(ax[1], wB[nb * 4 + 1], vd);
                vd = mfma32(ax[2], wB[nb * 4 + 2], vd);
                vd = mfma32(ax[3], wB[nb * 4 + 3], vd);
                const int cv = nb * 32 + cl;
                const float vb = nb ? vb1 : vb0;
#pragma unroll
                for (int rq = 0; rq < 4; ++rq) {
                    uint2 pk;
                    pk.x = cvtpk(vd[rq * 4 + 0] + vb, vd[rq * 4 + 1] + vb);
                    pk.y = cvtpk(vd[rq * 4 + 2] + vb, vd[rq * 4 + 3] + vb);
                    *(uint2*)&smem[VOFF + cv * 520 + tokb + rq * 8 + 4 * h5] = pk;
                }
            }
        }
        if (cc == 0) {
            __syncthreads();                  // (2) X0 readers done
            STX()
            __syncthreads();                  // (3) X1 visible
        }
    }
    __syncthreads();                          // (4) K/V complete

    // ---- attention: wave owns q = wid*32 + cl; m in 16 chunks of 32 ----
    B8 qB[2];
#pragma unroll
    for (int kc = 0; kc < 2; ++kc)
        qB[kc].u4 = *(const uint4*)&smem[kidx(wid * 32 + cl, 2 * kc + h5)];

    f32x16 ctx0 = z16, ctx1 = z16;
    float lsum = 0.f;

#pragma unroll 2
    for (int ci = 0; ci < 16; ++ci) {
        const int m0 = ci * 32;
        B8 kA0, kA1, va00, va01, va10, va11;
        kA0.u4  = *(const uint4*)&smem[kidx(m0 + cl, h5)];
        kA1.u4  = *(const uint4*)&smem[kidx(m0 + cl, 2 + h5)];
        va00.u4 = *(const uint4*)&smem[VOFF + cl * 520 + m0 + h5 * 8];
        va01.u4 = *(const uint4*)&smem[VOFF + cl * 520 + m0 + 16 + h5 * 8];
        va10.u4 = *(const uint4*)&smem[VOFF + (32 + cl) * 520 + m0 + h5 * 8];
        va11.u4 = *(const uint4*)&smem[VOFF + (32 + cl) * 520 + m0 + 16 + h5 * 8];

        __builtin_amdgcn_s_setprio(1);
        f32x16 s = mfma32(kA0, qB[0], z16);
        s = mfma32(kA1, qB[1], s);
        __builtin_amdgcn_s_setprio(0);

        float p[16];
#pragma unroll
        for (int i = 0; i < 16; ++i) p[i] = ex2(s[i]);
        lsum += (((p[0]+p[1])+(p[2]+p[3]))+((p[4]+p[5])+(p[6]+p[7])))
              + (((p[8]+p[9])+(p[10]+p[11]))+((p[12]+p[13])+(p[14]+p[15])));
        B8 pb0, pb1;
        build_b(p, pb0, pb1);

        __builtin_amdgcn_s_setprio(1);
        ctx0 = mfma32(va00, pb0, ctx0);
        ctx0 = mfma32(va01, pb1, ctx0);
        ctx1 = mfma32(va10, pb0, ctx1);
        ctx1 = mfma32(va11, pb1, ctx1);
        __builtin_amdgcn_s_setprio(0);
    }

    lsum += __shfl_xor(lsum, 32);
    const float inv = 1.0f / lsum;

    // out-proj A-frags + ctx -> B-frags in registers
    B8 aw[2][4];
#pragma unroll
    for (int cob = 0; cob < 2; ++cob)
#pragma unroll
        for (int kc = 0; kc < 4; ++kc)
            aw[cob][kc] = load_w8(wo + (cob * 32 + cl) * 64 + kc * 16 + h5 * 8, 1.0f);

    float pn[16];
    B8 cq[4];
#pragma unroll
    for (int i = 0; i < 16; ++i) pn[i] = ctx0[i] * inv;
    build_b(pn, cq[0], cq[1]);
#pragma unroll
    for (int i = 0; i < 16; ++i) pn[i] = ctx1[i] * inv;
    build_b(pn, cq[2], cq[3]);

    __syncthreads();                          // (5) K/V readers done; LDS -> fout slots

    float* fout = (float*)((char*)smem + wid * 8192);   // [64 co][32 q] f32
#pragma unroll
    for (int cob = 0; cob < 2; ++cob) {
        f32x16 od = mfma32(aw[cob][0], cq[0], z16);
        od = mfma32(aw[cob][1], cq[1], od);
        od = mfma32(aw[cob][2], cq[2], od);
        od = mfma32(aw[cob][3], cq[3], od);
#pragma unroll
        for (int r = 0; r < 16; ++r) {
            const int row = cob * 32 + (r & 3) + 8 * (r >> 2) + 4 * h5;
            fout[row * 32 + cl] = od[r];
        }
    }

    // coalesced-ish global store: wave covers hb = wid>>1, wb-half = wid&1 (bias added here)
    float* outw = out + base_vox + (size_t)(wid >> 1) * 4096 + (wid & 1) * 256;
#pragma unroll
    for (int it = 0; it < 8; ++it) {
        const int co = it * 8 + (lane >> 3);
        const int q4 = (lane & 7) * 4;
        float4 v4 = *(const float4*)&fout[co * 32 + q4];
        const float bco = bo[co];
        v4.x += bco; v4.y += bco; v4.z += bco; v4.w += bco;
        const int wb = (lane & 7) >> 1, db0 = (lane & 1) * 4;
        *(float4*)&outw[(size_t)co * 262144 + wb * 64 + db0] = v4;
    }
}

extern "C" void kernel_launch(void* const* d_in, const int* in_sizes, int n_in,
                              void* d_out, int out_size, void* d_ws, size_t ws_size,
                              hipStream_t stream) {
    const float* x  = (const float*)d_in[0];
    const float* wk = (const float*)d_in[1];
    const float* bk = (const float*)d_in[2];
    const float* wv = (const float*)d_in[3];
    const float* bv = (const float*)d_in[4];
    const float* wo = (const float*)d_in[5];
    const float* bo = (const float*)d_in[6];
    float* o = (float*)d_out;
    psab_fused<<<dim3(512), dim3(1024), 0, stream>>>(x, wk, bk, wv, bv, wo, bo, o);
}